// Round 1
// baseline (339.900 us; speedup 1.0000x reference)
//
#include <hip/hip_runtime.h>
#include <math.h>

#define BH 64
#define NN 8192
#define DD 64
#define MM 32

#define NROWS (BH*NN)            // 524288
#define NORMC 0.35355339059327379f   // 64^-0.25
#define RATIO 0.17677669529663689f   // 32^-0.5
#define EPSK  1e-4f
#define DIAGC 0.0625f                // 0.5 * 64^-0.5

#define CPB 16                   // chunks per batch in kv kernel
#define CHUNK 512                // rows per chunk
#define K2_BLOCKS (BH*CPB)       // 1024

__device__ __forceinline__ float wave_max(float v) {
  #pragma unroll
  for (int off = 32; off > 0; off >>= 1)
    v = fmaxf(v, __shfl_down(v, off, 64));
  return v;
}

// ---------------- K1: k_dash, global-max partials, optional s-cache ----------
__global__ __launch_bounds__(256) void k1_dash_max(
    const float* __restrict__ k, const float* __restrict__ proj,
    float* __restrict__ partialMax, float* __restrict__ sOut)
{
  const int t = threadIdx.x;
  const size_t row = (size_t)blockIdx.x * 256 + t;
  const float4* kr = (const float4*)(k + row * DD);
  float4 kq[16];
  #pragma unroll
  for (int i = 0; i < 16; ++i) kq[i] = kr[i];
  float ssq = 0.f;
  #pragma unroll
  for (int i = 0; i < 16; ++i)
    ssq += kq[i].x*kq[i].x + kq[i].y*kq[i].y + kq[i].z*kq[i].z + kq[i].w*kq[i].w;
  const float diag = DIAGC * ssq;

  float dash[MM];
  float mx = -3.4e38f;
  #pragma unroll
  for (int m = 0; m < MM; ++m) {
    const float4* pm = (const float4*)(proj + m * DD);
    float a = 0.f;
    #pragma unroll
    for (int i = 0; i < 16; ++i) {
      float4 p4 = pm[i];
      a = fmaf(kq[i].x, p4.x, a);
      a = fmaf(kq[i].y, p4.y, a);
      a = fmaf(kq[i].z, p4.z, a);
      a = fmaf(kq[i].w, p4.w, a);
    }
    a *= NORMC;
    mx = fmaxf(mx, a);
    dash[m] = a - diag;
  }
  if (sOut) {
    float4* so = (float4*)(sOut + row * MM);
    #pragma unroll
    for (int j = 0; j < 8; ++j)
      so[j] = make_float4(dash[4*j], dash[4*j+1], dash[4*j+2], dash[4*j+3]);
  }
  mx = wave_max(mx);
  __shared__ float wmax[4];
  if ((t & 63) == 0) wmax[t >> 6] = mx;
  __syncthreads();
  if (t == 0)
    partialMax[blockIdx.x] = fmaxf(fmaxf(wmax[0], wmax[1]), fmaxf(wmax[2], wmax[3]));
}

// ---------------- K1b: reduce partial maxes -> global max -------------------
__global__ __launch_bounds__(256) void k1b_reduce_max(
    const float* __restrict__ partialMax, float* __restrict__ gmax)
{
  const int t = threadIdx.x;
  float mx = -3.4e38f;
  for (int i = t; i < 2048; i += 256) mx = fmaxf(mx, partialMax[i]);
  mx = wave_max(mx);
  __shared__ float wmax[4];
  if ((t & 63) == 0) wmax[t >> 6] = mx;
  __syncthreads();
  if (t == 0)
    *gmax = fmaxf(fmaxf(wmax[0], wmax[1]), fmaxf(wmax[2], wmax[3]));
}

// ---------------- K2: kp, then kv/ksum partial reduction --------------------
template<bool USE_S>
__global__ __launch_bounds__(256) void k2_kv(
    const float* __restrict__ k, const float* __restrict__ v,
    const float* __restrict__ proj, const float* __restrict__ sBuf,
    const float* __restrict__ gmaxPtr,
    float* __restrict__ kvPart, float* __restrict__ ksPart)
{
  __shared__ float kpL[8][258][4];   // [m_blk][row][m_lo], padded: 33 KB
  const int t = threadIdx.x;
  const int b = blockIdx.x >> 4;
  const int c = blockIdx.x & (CPB - 1);
  const size_t base = (size_t)b * NN + (size_t)c * CHUNK;
  const float gmax = *gmaxPtr;

  const int dg = t & 7, mg = (t >> 3) & 7, ng = t >> 6;
  float acc[4][8];
  #pragma unroll
  for (int j = 0; j < 4; ++j)
    #pragma unroll
    for (int e = 0; e < 8; ++e) acc[j][e] = 0.f;
  float ksacc[4] = {0.f, 0.f, 0.f, 0.f};

  for (int st = 0; st < CHUNK / 256; ++st) {
    const size_t rbase = base + st * 256;
    // ---- phase A: kp for 256 rows -> LDS
    {
      const size_t row = rbase + t;
      float p[MM];
      if (USE_S) {
        const float4* sr = (const float4*)(sBuf + row * MM);
        #pragma unroll
        for (int j = 0; j < 8; ++j) {
          float4 s4 = sr[j];
          p[4*j]   = RATIO * (__expf(s4.x - gmax) + EPSK);
          p[4*j+1] = RATIO * (__expf(s4.y - gmax) + EPSK);
          p[4*j+2] = RATIO * (__expf(s4.z - gmax) + EPSK);
          p[4*j+3] = RATIO * (__expf(s4.w - gmax) + EPSK);
        }
      } else {
        const float4* kr = (const float4*)(k + row * DD);
        float4 kq[16];
        #pragma unroll
        for (int i = 0; i < 16; ++i) kq[i] = kr[i];
        float ssq = 0.f;
        #pragma unroll
        for (int i = 0; i < 16; ++i)
          ssq += kq[i].x*kq[i].x + kq[i].y*kq[i].y + kq[i].z*kq[i].z + kq[i].w*kq[i].w;
        const float dsub = DIAGC * ssq + gmax;
        #pragma unroll
        for (int m = 0; m < MM; ++m) {
          const float4* pm = (const float4*)(proj + m * DD);
          float a = 0.f;
          #pragma unroll
          for (int i = 0; i < 16; ++i) {
            float4 p4 = pm[i];
            a = fmaf(kq[i].x, p4.x, a);
            a = fmaf(kq[i].y, p4.y, a);
            a = fmaf(kq[i].z, p4.z, a);
            a = fmaf(kq[i].w, p4.w, a);
          }
          p[m] = RATIO * (__expf(fmaf(a, NORMC, -dsub)) + EPSK);
        }
      }
      #pragma unroll
      for (int mb = 0; mb < 8; ++mb) {
        kpL[mb][t][0] = p[4*mb];
        kpL[mb][t][1] = p[4*mb+1];
        kpL[mb][t][2] = p[4*mb+2];
        kpL[mb][t][3] = p[4*mb+3];
      }
    }
    __syncthreads();
    // ---- phase B: register-tiled outer-product accumulation
    {
      #pragma unroll 4
      for (int i = 0; i < 64; ++i) {
        const int n = (ng << 6) + i;
        const float4 kp4 = *(const float4*)&kpL[mg][n][0];
        const float4* vr = (const float4*)(v + (rbase + n) * DD + dg * 8);
        const float4 va = vr[0], vb = vr[1];
        #pragma unroll
        for (int j = 0; j < 4; ++j) {
          const float pj = (&kp4.x)[j];
          acc[j][0] = fmaf(pj, va.x, acc[j][0]);
          acc[j][1] = fmaf(pj, va.y, acc[j][1]);
          acc[j][2] = fmaf(pj, va.z, acc[j][2]);
          acc[j][3] = fmaf(pj, va.w, acc[j][3]);
          acc[j][4] = fmaf(pj, vb.x, acc[j][4]);
          acc[j][5] = fmaf(pj, vb.y, acc[j][5]);
          acc[j][6] = fmaf(pj, vb.z, acc[j][6]);
          acc[j][7] = fmaf(pj, vb.w, acc[j][7]);
          ksacc[j] += pj;
        }
      }
    }
    __syncthreads();
  }

  // ---- block reduction over the 4 n-groups
  float* red = &kpL[0][0][0];   // reuse LDS: need 8192 floats (have 8256)
  #pragma unroll
  for (int j = 0; j < 4; ++j)
    #pragma unroll
    for (int e = 0; e < 8; ++e)
      red[t * 32 + j * 8 + e] = acc[j][e];
  __syncthreads();
  #pragma unroll
  for (int ii = 0; ii < 8; ++ii) {
    const int o = t + 256 * ii;
    const int m = o >> 6, d = o & 63;
    const int mg2 = m >> 2, j2 = m & 3, dg2 = d >> 3, e2 = d & 7;
    float s = 0.f;
    #pragma unroll
    for (int g = 0; g < 4; ++g)
      s += red[(dg2 + 8 * mg2 + 64 * g) * 32 + j2 * 8 + e2];
    kvPart[(size_t)blockIdx.x * 2048 + o] = s;
  }
  __syncthreads();
  if (dg == 0) {
    #pragma unroll
    for (int j = 0; j < 4; ++j)
      red[ng * 32 + mg * 4 + j] = ksacc[j];
  }
  __syncthreads();
  if (t < 32) {
    float s = red[t] + red[32 + t] + red[64 + t] + red[96 + t];
    ksPart[blockIdx.x * 32 + t] = s;
  }
}

// ---------------- K2b: reduce chunk partials -> kv, ksum --------------------
__global__ __launch_bounds__(256) void k2b_reduce(
    const float* __restrict__ kvPart, const float* __restrict__ ksPart,
    float* __restrict__ kvF, float* __restrict__ ksF)
{
  const int b = blockIdx.x, t = threadIdx.x;
  #pragma unroll
  for (int ii = 0; ii < 8; ++ii) {
    const int o = t + 256 * ii;
    float s = 0.f;
    for (int c = 0; c < CPB; ++c)
      s += kvPart[((size_t)(b * CPB + c)) * 2048 + o];
    kvF[b * 2048 + o] = s;
  }
  if (t < 32) {
    float s = 0.f;
    for (int c = 0; c < CPB; ++c)
      s += ksPart[(b * CPB + c) * 32 + t];
    ksF[b * 32 + t] = s;
  }
}

// ---------------- K3: qp, num/den, output -----------------------------------
__global__ __launch_bounds__(256) void k3_out(
    const float* __restrict__ q, const float* __restrict__ proj,
    const float* __restrict__ kvF, const float* __restrict__ ksF,
    float* __restrict__ out)
{
  const int t = threadIdx.x;
  const size_t row = (size_t)blockIdx.x * 256 + t;
  const int b = (int)(row >> 13);
  const float4* qr = (const float4*)(q + row * DD);
  float4 qq[16];
  #pragma unroll
  for (int i = 0; i < 16; ++i) qq[i] = qr[i];
  float ssq = 0.f;
  #pragma unroll
  for (int i = 0; i < 16; ++i)
    ssq += qq[i].x*qq[i].x + qq[i].y*qq[i].y + qq[i].z*qq[i].z + qq[i].w*qq[i].w;
  const float diag = DIAGC * ssq;

  float dash[MM];
  float mx = -3.4e38f;
  #pragma unroll
  for (int m = 0; m < MM; ++m) {
    const float4* pm = (const float4*)(proj + m * DD);
    float a = 0.f;
    #pragma unroll
    for (int i = 0; i < 16; ++i) {
      float4 p4 = pm[i];
      a = fmaf(qq[i].x, p4.x, a);
      a = fmaf(qq[i].y, p4.y, a);
      a = fmaf(qq[i].z, p4.z, a);
      a = fmaf(qq[i].w, p4.w, a);
    }
    a *= NORMC;
    dash[m] = a;
    mx = fmaxf(mx, a);
  }
  const float sub = diag + mx;
  float p[MM];
  #pragma unroll
  for (int m = 0; m < MM; ++m)
    p[m] = RATIO * (__expf(dash[m] - sub) + EPSK);

  const float* kvb = kvF + (size_t)b * 2048;
  const float* ksb = ksF + b * 32;
  float num[DD];
  #pragma unroll
  for (int d = 0; d < DD; ++d) num[d] = 0.f;
  float den = 0.f;
  #pragma unroll
  for (int m = 0; m < MM; ++m) {
    const float pm = p[m];
    const float* kvr = kvb + m * 64;
    #pragma unroll
    for (int d = 0; d < DD; ++d)
      num[d] = fmaf(pm, kvr[d], num[d]);
    den = fmaf(pm, ksb[m], den);
  }
  const float inv = 1.0f / den;
  float4* orow = (float4*)(out + row * DD);
  #pragma unroll
  for (int i = 0; i < 16; ++i)
    orow[i] = make_float4(num[4*i]*inv, num[4*i+1]*inv, num[4*i+2]*inv, num[4*i+3]*inv);
}

// ---------------- host ------------------------------------------------------
extern "C" void kernel_launch(void* const* d_in, const int* in_sizes, int n_in,
                              void* d_out, int out_size, void* d_ws, size_t ws_size,
                              hipStream_t stream) {
  const float* q    = (const float*)d_in[0];
  const float* k    = (const float*)d_in[1];
  const float* v    = (const float*)d_in[2];
  const float* proj = (const float*)d_in[3];
  float* out = (float*)d_out;
  float* ws  = (float*)d_ws;

  float* partialMax = ws;                  // 2048 floats
  float* gmax       = ws + 2048;           // 1
  float* kvPart     = ws + 4096;           // 1024*2048
  float* ksPart     = kvPart + 2097152;    // 1024*32
  float* kvF        = ksPart + 32768;      // 64*2048
  float* ksF        = kvF + 131072;        // 64*32
  const size_t baseFloats = 4096 + 2097152 + 32768 + 131072 + 2048;
  float* sBuf       = ws + baseFloats;     // 524288*32 floats (64 MB) if it fits
  const bool useS = ws_size >= (baseFloats + (size_t)NROWS * MM) * sizeof(float);

  k1_dash_max<<<NROWS / 256, 256, 0, stream>>>(k, proj, partialMax,
                                               useS ? sBuf : nullptr);
  k1b_reduce_max<<<1, 256, 0, stream>>>(partialMax, gmax);
  if (useS)
    k2_kv<true><<<K2_BLOCKS, 256, 0, stream>>>(k, v, proj, sBuf, gmax, kvPart, ksPart);
  else
    k2_kv<false><<<K2_BLOCKS, 256, 0, stream>>>(k, v, proj, sBuf, gmax, kvPart, ksPart);
  k2b_reduce<<<BH, 256, 0, stream>>>(kvPart, ksPart, kvF, ksF);
  k3_out<<<NROWS / 256, 256, 0, stream>>>(q, proj, kvF, ksF, out);
}

// Round 2
// 264.449 us; speedup vs baseline: 1.2853x; 1.2853x over previous
//
#include <hip/hip_runtime.h>
#include <math.h>

#define BH 64
#define NN 8192
#define DD 64
#define MM 32

#define NROWS (BH*NN)            // 524288
#define NORMC 0.35355339059327379f   // 64^-0.25
#define RATIO 0.17677669529663689f   // 32^-0.5
#define EPSK  1e-4f
#define DIAGC 0.0625f                // 0.5 * 64^-0.5

#define CPB 16                   // chunks per batch in kv kernel
#define CHUNK 512                // rows per chunk
#define K2_BLOCKS (BH*CPB)       // 1024

__device__ __forceinline__ float wave_max(float v) {
  #pragma unroll
  for (int off = 32; off > 0; off >>= 1)
    v = fmaxf(v, __shfl_down(v, off, 64));
  return v;
}

// ---------------- K1: k_dash, global-max partials, optional s-cache ----------
__global__ __launch_bounds__(256) void k1_dash_max(
    const float* __restrict__ k, const float* __restrict__ proj,
    float* __restrict__ partialMax, float* __restrict__ sOut)
{
  const int t = threadIdx.x;
  const size_t row = (size_t)blockIdx.x * 256 + t;
  const float4* kr = (const float4*)(k + row * DD);
  float4 kq[16];
  #pragma unroll
  for (int i = 0; i < 16; ++i) kq[i] = kr[i];
  float ssq = 0.f;
  #pragma unroll
  for (int i = 0; i < 16; ++i)
    ssq += kq[i].x*kq[i].x + kq[i].y*kq[i].y + kq[i].z*kq[i].z + kq[i].w*kq[i].w;
  const float diag = DIAGC * ssq;

  float dash[MM];
  float mx = -3.4e38f;
  #pragma unroll
  for (int m = 0; m < MM; ++m) {
    const float4* pm = (const float4*)(proj + m * DD);
    float a = 0.f;
    #pragma unroll
    for (int i = 0; i < 16; ++i) {
      float4 p4 = pm[i];
      a = fmaf(kq[i].x, p4.x, a);
      a = fmaf(kq[i].y, p4.y, a);
      a = fmaf(kq[i].z, p4.z, a);
      a = fmaf(kq[i].w, p4.w, a);
    }
    a *= NORMC;
    mx = fmaxf(mx, a);
    dash[m] = a - diag;
  }
  if (sOut) {
    float4* so = (float4*)(sOut + row * MM);
    #pragma unroll
    for (int j = 0; j < 8; ++j)
      so[j] = make_float4(dash[4*j], dash[4*j+1], dash[4*j+2], dash[4*j+3]);
  }
  mx = wave_max(mx);
  __shared__ float wmax[4];
  if ((t & 63) == 0) wmax[t >> 6] = mx;
  __syncthreads();
  if (t == 0)
    partialMax[blockIdx.x] = fmaxf(fmaxf(wmax[0], wmax[1]), fmaxf(wmax[2], wmax[3]));
}

// ---------------- K1b: reduce partial maxes -> global max -------------------
__global__ __launch_bounds__(256) void k1b_reduce_max(
    const float* __restrict__ partialMax, float* __restrict__ gmax)
{
  const int t = threadIdx.x;
  float mx = -3.4e38f;
  for (int i = t; i < 2048; i += 256) mx = fmaxf(mx, partialMax[i]);
  mx = wave_max(mx);
  __shared__ float wmax[4];
  if ((t & 63) == 0) wmax[t >> 6] = mx;
  __syncthreads();
  if (t == 0)
    *gmax = fmaxf(fmaxf(wmax[0], wmax[1]), fmaxf(wmax[2], wmax[3]));
}

// ---------------- K2: kp, then kv/ksum partial reduction --------------------
template<bool USE_S>
__global__ __launch_bounds__(256) void k2_kv(
    const float* __restrict__ k, const float* __restrict__ v,
    const float* __restrict__ proj, const float* __restrict__ sBuf,
    const float* __restrict__ gmaxPtr,
    float* __restrict__ kvPart, float* __restrict__ ksPart)
{
  __shared__ float kpL[8][258][4];   // [m_blk][row][m_lo], padded: 33 KB
  const int t = threadIdx.x;
  const int b = blockIdx.x >> 4;
  const int c = blockIdx.x & (CPB - 1);
  const size_t base = (size_t)b * NN + (size_t)c * CHUNK;
  const float gmax = *gmaxPtr;

  const int dg = t & 7, mg = (t >> 3) & 7, ng = t >> 6;
  float acc[4][8];
  #pragma unroll
  for (int j = 0; j < 4; ++j)
    #pragma unroll
    for (int e = 0; e < 8; ++e) acc[j][e] = 0.f;
  float ksacc[4] = {0.f, 0.f, 0.f, 0.f};

  for (int st = 0; st < CHUNK / 256; ++st) {
    const size_t rbase = base + st * 256;
    // ---- phase A: kp for 256 rows -> LDS
    {
      const size_t row = rbase + t;
      float p[MM];
      if (USE_S) {
        const float4* sr = (const float4*)(sBuf + row * MM);
        #pragma unroll
        for (int j = 0; j < 8; ++j) {
          float4 s4 = sr[j];
          p[4*j]   = RATIO * (__expf(s4.x - gmax) + EPSK);
          p[4*j+1] = RATIO * (__expf(s4.y - gmax) + EPSK);
          p[4*j+2] = RATIO * (__expf(s4.z - gmax) + EPSK);
          p[4*j+3] = RATIO * (__expf(s4.w - gmax) + EPSK);
        }
      } else {
        const float4* kr = (const float4*)(k + row * DD);
        float4 kq[16];
        #pragma unroll
        for (int i = 0; i < 16; ++i) kq[i] = kr[i];
        float ssq = 0.f;
        #pragma unroll
        for (int i = 0; i < 16; ++i)
          ssq += kq[i].x*kq[i].x + kq[i].y*kq[i].y + kq[i].z*kq[i].z + kq[i].w*kq[i].w;
        const float dsub = DIAGC * ssq + gmax;
        #pragma unroll
        for (int m = 0; m < MM; ++m) {
          const float4* pm = (const float4*)(proj + m * DD);
          float a = 0.f;
          #pragma unroll
          for (int i = 0; i < 16; ++i) {
            float4 p4 = pm[i];
            a = fmaf(kq[i].x, p4.x, a);
            a = fmaf(kq[i].y, p4.y, a);
            a = fmaf(kq[i].z, p4.z, a);
            a = fmaf(kq[i].w, p4.w, a);
          }
          p[m] = RATIO * (__expf(fmaf(a, NORMC, -dsub)) + EPSK);
        }
      }
      #pragma unroll
      for (int mb = 0; mb < 8; ++mb) {
        kpL[mb][t][0] = p[4*mb];
        kpL[mb][t][1] = p[4*mb+1];
        kpL[mb][t][2] = p[4*mb+2];
        kpL[mb][t][3] = p[4*mb+3];
      }
    }
    __syncthreads();
    // ---- phase B: register-tiled outer-product accumulation
    {
      #pragma unroll 4
      for (int i = 0; i < 64; ++i) {
        const int n = (ng << 6) + i;
        const float4 kp4 = *(const float4*)&kpL[mg][n][0];
        const float4* vr = (const float4*)(v + (rbase + n) * DD + dg * 8);
        const float4 va = vr[0], vb = vr[1];
        #pragma unroll
        for (int j = 0; j < 4; ++j) {
          const float pj = (&kp4.x)[j];
          acc[j][0] = fmaf(pj, va.x, acc[j][0]);
          acc[j][1] = fmaf(pj, va.y, acc[j][1]);
          acc[j][2] = fmaf(pj, va.z, acc[j][2]);
          acc[j][3] = fmaf(pj, va.w, acc[j][3]);
          acc[j][4] = fmaf(pj, vb.x, acc[j][4]);
          acc[j][5] = fmaf(pj, vb.y, acc[j][5]);
          acc[j][6] = fmaf(pj, vb.z, acc[j][6]);
          acc[j][7] = fmaf(pj, vb.w, acc[j][7]);
          ksacc[j] += pj;
        }
      }
    }
    __syncthreads();
  }

  // ---- block reduction over the 4 n-groups
  float* red = &kpL[0][0][0];   // reuse LDS: need 8192 floats (have 8256)
  #pragma unroll
  for (int j = 0; j < 4; ++j)
    #pragma unroll
    for (int e = 0; e < 8; ++e)
      red[t * 32 + j * 8 + e] = acc[j][e];
  __syncthreads();
  #pragma unroll
  for (int ii = 0; ii < 8; ++ii) {
    const int o = t + 256 * ii;
    const int m = o >> 6, d = o & 63;
    const int mg2 = m >> 2, j2 = m & 3, dg2 = d >> 3, e2 = d & 7;
    float s = 0.f;
    #pragma unroll
    for (int g = 0; g < 4; ++g)
      s += red[(dg2 + 8 * mg2 + 64 * g) * 32 + j2 * 8 + e2];
    kvPart[(size_t)blockIdx.x * 2048 + o] = s;
  }
  __syncthreads();
  if (dg == 0) {
    #pragma unroll
    for (int j = 0; j < 4; ++j)
      red[ng * 32 + mg * 4 + j] = ksacc[j];
  }
  __syncthreads();
  if (t < 32) {
    float s = red[t] + red[32 + t] + red[64 + t] + red[96 + t];
    ksPart[blockIdx.x * 32 + t] = s;
  }
}

// ---------------- K2b: reduce chunk partials -> kv, ksum --------------------
__global__ __launch_bounds__(256) void k2b_reduce(
    const float* __restrict__ kvPart, const float* __restrict__ ksPart,
    float* __restrict__ kvF, float* __restrict__ ksF)
{
  const int b = blockIdx.x, t = threadIdx.x;
  #pragma unroll
  for (int ii = 0; ii < 8; ++ii) {
    const int o = t + 256 * ii;
    float s = 0.f;
    for (int c = 0; c < CPB; ++c)
      s += kvPart[((size_t)(b * CPB + c)) * 2048 + o];
    kvF[b * 2048 + o] = s;
  }
  if (t < 32) {
    float s = 0.f;
    for (int c = 0; c < CPB; ++c)
      s += ksPart[(b * CPB + c) * 32 + t];
    ksF[b * 32 + t] = s;
  }
}

// ---------------- K3: qp, num/den, output -----------------------------------
// b derived from blockIdx ONLY -> kv/ksum pointers are wave-uniform -> the
// compiler scalarizes those loads to s_load (SGPR operand feeds v_fmac).
// Numerator tiled into 4 chunks of 16 so peak live VGPRs ~ max(qq64+p32,
// p32+acc16) -> no scratch spill.
__global__ __launch_bounds__(256) void k3_out(
    const float* __restrict__ q, const float* __restrict__ proj,
    const float* __restrict__ kvF, const float* __restrict__ ksF,
    float* __restrict__ out)
{
  const int t = threadIdx.x;
  const int b = blockIdx.x >> 5;              // 32 blocks of 256 rows per batch
  const size_t row = (size_t)blockIdx.x * 256 + t;
  const float* __restrict__ kvb = kvF + (size_t)b * 2048;
  const float* __restrict__ ksb = ksF + b * 32;

  const float4* qr = (const float4*)(q + row * DD);
  float4 qq[16];
  #pragma unroll
  for (int i = 0; i < 16; ++i) qq[i] = qr[i];
  float ssq = 0.f;
  #pragma unroll
  for (int i = 0; i < 16; ++i)
    ssq += qq[i].x*qq[i].x + qq[i].y*qq[i].y + qq[i].z*qq[i].z + qq[i].w*qq[i].w;
  const float diag = DIAGC * ssq;

  float p[MM];
  float mx = -3.4e38f;
  #pragma unroll
  for (int m = 0; m < MM; ++m) {
    const float4* pm = (const float4*)(proj + m * DD);
    float a = 0.f;
    #pragma unroll
    for (int i = 0; i < 16; ++i) {
      float4 p4 = pm[i];
      a = fmaf(qq[i].x, p4.x, a);
      a = fmaf(qq[i].y, p4.y, a);
      a = fmaf(qq[i].z, p4.z, a);
      a = fmaf(qq[i].w, p4.w, a);
    }
    a *= NORMC;
    p[m] = a;
    mx = fmaxf(mx, a);
  }
  const float sub = diag + mx;
  #pragma unroll
  for (int m = 0; m < MM; ++m)
    p[m] = RATIO * (__expf(p[m] - sub) + EPSK);

  float den = 0.f;
  #pragma unroll
  for (int m = 0; m < MM; ++m)
    den = fmaf(p[m], ksb[m], den);
  const float inv = 1.0f / den;

  float4* orow = (float4*)(out + row * DD);
  #pragma unroll
  for (int c = 0; c < 4; ++c) {
    float a0=0.f,a1=0.f,a2=0.f,a3=0.f,a4=0.f,a5=0.f,a6=0.f,a7=0.f;
    float a8=0.f,a9=0.f,a10=0.f,a11=0.f,a12=0.f,a13=0.f,a14=0.f,a15=0.f;
    #pragma unroll
    for (int m = 0; m < MM; ++m) {
      const float pm = p[m];
      const float* __restrict__ kr = kvb + m * 64 + c * 16;
      a0  = fmaf(pm, kr[0],  a0);
      a1  = fmaf(pm, kr[1],  a1);
      a2  = fmaf(pm, kr[2],  a2);
      a3  = fmaf(pm, kr[3],  a3);
      a4  = fmaf(pm, kr[4],  a4);
      a5  = fmaf(pm, kr[5],  a5);
      a6  = fmaf(pm, kr[6],  a6);
      a7  = fmaf(pm, kr[7],  a7);
      a8  = fmaf(pm, kr[8],  a8);
      a9  = fmaf(pm, kr[9],  a9);
      a10 = fmaf(pm, kr[10], a10);
      a11 = fmaf(pm, kr[11], a11);
      a12 = fmaf(pm, kr[12], a12);
      a13 = fmaf(pm, kr[13], a13);
      a14 = fmaf(pm, kr[14], a14);
      a15 = fmaf(pm, kr[15], a15);
    }
    orow[c*4+0] = make_float4(a0*inv,  a1*inv,  a2*inv,  a3*inv);
    orow[c*4+1] = make_float4(a4*inv,  a5*inv,  a6*inv,  a7*inv);
    orow[c*4+2] = make_float4(a8*inv,  a9*inv,  a10*inv, a11*inv);
    orow[c*4+3] = make_float4(a12*inv, a13*inv, a14*inv, a15*inv);
  }
}

// ---------------- host ------------------------------------------------------
extern "C" void kernel_launch(void* const* d_in, const int* in_sizes, int n_in,
                              void* d_out, int out_size, void* d_ws, size_t ws_size,
                              hipStream_t stream) {
  const float* q    = (const float*)d_in[0];
  const float* k    = (const float*)d_in[1];
  const float* v    = (const float*)d_in[2];
  const float* proj = (const float*)d_in[3];
  float* out = (float*)d_out;
  float* ws  = (float*)d_ws;

  float* partialMax = ws;                  // 2048 floats
  float* gmax       = ws + 2048;           // 1
  float* kvPart     = ws + 4096;           // 1024*2048
  float* ksPart     = kvPart + 2097152;    // 1024*32
  float* kvF        = ksPart + 32768;      // 64*2048
  float* ksF        = kvF + 131072;        // 64*32
  const size_t baseFloats = 4096 + 2097152 + 32768 + 131072 + 2048;
  float* sBuf       = ws + baseFloats;     // 524288*32 floats (64 MB) if it fits
  const bool useS = ws_size >= (baseFloats + (size_t)NROWS * MM) * sizeof(float);

  k1_dash_max<<<NROWS / 256, 256, 0, stream>>>(k, proj, partialMax,
                                               useS ? sBuf : nullptr);
  k1b_reduce_max<<<1, 256, 0, stream>>>(partialMax, gmax);
  if (useS)
    k2_kv<true><<<K2_BLOCKS, 256, 0, stream>>>(k, v, proj, sBuf, gmax, kvPart, ksPart);
  else
    k2_kv<false><<<K2_BLOCKS, 256, 0, stream>>>(k, v, proj, sBuf, gmax, kvPart, ksPart);
  k2b_reduce<<<BH, 256, 0, stream>>>(kvPart, ksPart, kvF, ksF);
  k3_out<<<NROWS / 256, 256, 0, stream>>>(q, proj, kvF, ksF, out);
}